// Round 9
// baseline (116.795 us; speedup 1.0000x reference)
//
#include <hip/hip_runtime.h>

#define D_MODEL 1024
#define N_HEADS 16
#define HD 64
#define T_SEQ 2048
#define B_SZ 2
#define M_ROWS (B_SZ*T_SEQ)   // 4096
#define ALIBI_M 0.0625f
#define SM_SCALE 0.125f       // 1/sqrt(64)
#define WIN 512               // ALiBi window: dropped keys have rel mass < 1e-7
#define LOG2E 1.4426950408889634f

typedef float f32x4 __attribute__((ext_vector_type(4)));
typedef float f32x16 __attribute__((ext_vector_type(16)));
typedef short bf16x8 __attribute__((ext_vector_type(8)));

__device__ inline unsigned int f2bf(float f) {
  union { float f; unsigned int u; } v; v.f = f;
  return (v.u + 0x7fffu + ((v.u >> 16) & 1u)) >> 16;  // RNE
}

__device__ inline unsigned cvtpk(float lo, float hi) {
  unsigned r;
  asm("v_cvt_pk_bf16_f32 %0, %1, %2" : "=v"(r) : "v"(lo), "v"(hi));
  return r;
}

#define GLOAD_LDS16(g, l) __builtin_amdgcn_global_load_lds( \
    (const __attribute__((address_space(1))) void*)(g), \
    (__attribute__((address_space(3))) void*)(l), 16, 0, 0)

// Merged conversion: x (chunks 0-3) + Wq/Wk/Wv -> wqkv + Wo -> wob.
__global__ void cvt_all(const float* __restrict__ x, const float* __restrict__ Wq,
                        const float* __restrict__ Wk, const float* __restrict__ Wv,
                        const float* __restrict__ Wo, ushort* __restrict__ xbf,
                        ushort* __restrict__ wqkv, ushort* __restrict__ wob) {
  int i = blockIdx.x * blockDim.x + threadIdx.x;
  int c = i >> 18;              // 256K float4 = one 1024x1024 matrix per chunk
  int r = i & 0x3FFFF;
  const float* s; ushort* d;
  if (c < 4)       { s = x  + (size_t)i*4; d = xbf  + (size_t)i*4; }
  else if (c == 4) { s = Wq + (size_t)r*4; d = wqkv + (size_t)r*4; }
  else if (c == 5) { s = Wk + (size_t)r*4; d = wqkv + 1048576 + (size_t)r*4; }
  else if (c == 6) { s = Wv + (size_t)r*4; d = wqkv + 2097152 + (size_t)r*4; }
  else             { s = Wo + (size_t)r*4; d = wob  + (size_t)r*4; }
  float4 v = *reinterpret_cast<const float4*>(s);
  uint2 o;
  o.x = f2bf(v.x) | (f2bf(v.y) << 16);
  o.y = f2bf(v.z) | (f2bf(v.w) << 16);
  *reinterpret_cast<uint2*>(d) = o;
}

// Fused QKV GEMM (round-8 proven): BK=64 single-buffer, both-sides XOR swizzle.
__global__ __launch_bounds__(256) void gemm_qkv(const ushort* __restrict__ A,
    const ushort* __restrict__ W, const float* __restrict__ bqp,
    const float* __restrict__ bkp, const float* __restrict__ bvp,
    ushort* __restrict__ qk_out, ushort* __restrict__ vt_out) {
  __shared__ ushort As[128*64];   // 16 KB
  __shared__ ushort Bs[128*64];   // 16 KB
  const int tid = threadIdx.x, lane = tid & 63, wid = tid >> 6;
  const int lr = lane & 15, lc = lane >> 4;
  const int m0 = blockIdx.y * 128, n0 = blockIdx.x * 128;
  const int wm = (wid >> 1) * 64, wn = (wid & 1) * 64;
  const int which = n0 >> 10;
  const int srow = wid*32 + (lane >> 3);
  const int scol = ((lane & 7) ^ (lane >> 3)) * 8;
  const ushort* Ab = A + (size_t)(m0 + srow) * D_MODEL + scol;
  const ushort* Wb = W + (size_t)(n0 + srow) * D_MODEL + scol;
  const int x0 = (lc ^ (lr & 7)) * 8, x1 = ((4 + lc) ^ (lr & 7)) * 8;

  f32x4 acc[4][4] = {};

  for (int kt = 0; kt < 16; ++kt) {
    const int ko = kt * 64;
    #pragma unroll
    for (int rd = 0; rd < 4; ++rd) {
      GLOAD_LDS16(Ab + (size_t)(rd*8)*D_MODEL + ko, &As[(wid*32 + rd*8)*64]);
      GLOAD_LDS16(Wb + (size_t)(rd*8)*D_MODEL + ko, &Bs[(wid*32 + rd*8)*64]);
    }
    __syncthreads();
    #pragma unroll
    for (int ks = 0; ks < 2; ++ks) {
      const int xc = ks ? x1 : x0;
      bf16x8 af[4], wf[4];
      #pragma unroll
      for (int i = 0; i < 4; ++i)
        af[i] = *reinterpret_cast<const bf16x8*>(&As[(wm + i*16 + lr)*64 + xc]);
      #pragma unroll
      for (int j = 0; j < 4; ++j)
        wf[j] = *reinterpret_cast<const bf16x8*>(&Bs[(wn + j*16 + lr)*64 + xc]);
      if (which == 2) {
        #pragma unroll
        for (int i = 0; i < 4; ++i)
          #pragma unroll
          for (int j = 0; j < 4; ++j)
            acc[i][j] = __builtin_amdgcn_mfma_f32_16x16x32_bf16(af[i], wf[j], acc[i][j], 0, 0, 0);
      } else {
        #pragma unroll
        for (int i = 0; i < 4; ++i)
          #pragma unroll
          for (int j = 0; j < 4; ++j)
            acc[i][j] = __builtin_amdgcn_mfma_f32_16x16x32_bf16(wf[j], af[i], acc[i][j], 0, 0, 0);
      }
    }
    __syncthreads();
  }

  if (which < 2) {
    const float* bp = which ? bkp : bqp;
    #pragma unroll
    for (int i = 0; i < 4; ++i) {
      int m = m0 + wm + i*16 + lr;
      int bb = m >> 11, t = m & (T_SEQ-1);
      #pragma unroll
      for (int j = 0; j < 4; ++j) {
        int nl = (n0 & 1023) + wn + j*16 + lc*4;
        int h = nl >> 6, d0 = nl & 63;
        uint2 ov;
        ov.x = f2bf(acc[i][j][0] + bp[nl  ]) | (f2bf(acc[i][j][1] + bp[nl+1]) << 16);
        ov.y = f2bf(acc[i][j][2] + bp[nl+2]) | (f2bf(acc[i][j][3] + bp[nl+3]) << 16);
        *reinterpret_cast<uint2*>(&qk_out[(size_t)which*4194304 +
            (((size_t)bb*N_HEADS + h)*T_SEQ + t)*HD + d0]) = ov;
      }
    }
  } else {
    #pragma unroll
    for (int i = 0; i < 4; ++i) {
      int mb = m0 + wm + i*16 + lc*4;
      int bb = mb >> 11, t0 = mb & (T_SEQ-1);
      #pragma unroll
      for (int j = 0; j < 4; ++j) {
        int n = (n0 & 1023) + wn + j*16 + lr;
        int h = n >> 6, d = n & 63;
        float bias = bvp[n];
        uint2 ov;
        ov.x = f2bf(acc[i][j][0] + bias) | (f2bf(acc[i][j][1] + bias) << 16);
        ov.y = f2bf(acc[i][j][2] + bias) | (f2bf(acc[i][j][3] + bias) << 16);
        *reinterpret_cast<uint2*>(&vt_out[
            (((size_t)bb*N_HEADS + h)*HD + d)*T_SEQ + t0]) = ov;
      }
    }
  }
}

// O-projection (round-8 proven): 128x64 tile, BK=64 single-buffer, swizzled.
__global__ __launch_bounds__(256) void gemm_out(const ushort* __restrict__ A,
    const ushort* __restrict__ W, const float* __restrict__ bop,
    float* __restrict__ outp) {
  __shared__ ushort As[128*64];
  __shared__ ushort Bs[64*64];
  const int tid = threadIdx.x, lane = tid & 63, wid = tid >> 6;
  const int lr = lane & 15, lc = lane >> 4;
  const int m0 = blockIdx.y * 128, n0 = blockIdx.x * 64;
  const int wm = wid * 32;
  const int scol = ((lane & 7) ^ (lane >> 3)) * 8;
  const ushort* Ab = A + (size_t)(m0 + wid*32 + (lane >> 3)) * D_MODEL + scol;
  const ushort* Wb = W + (size_t)(n0 + wid*16 + (lane >> 3)) * D_MODEL + scol;
  const int x0 = (lc ^ (lr & 7)) * 8, x1 = ((4 + lc) ^ (lr & 7)) * 8;

  f32x4 acc[2][4] = {};

  for (int kt = 0; kt < 16; ++kt) {
    const int ko = kt * 64;
    #pragma unroll
    for (int rd = 0; rd < 4; ++rd)
      GLOAD_LDS16(Ab + (size_t)(rd*8)*D_MODEL + ko, &As[(wid*32 + rd*8)*64]);
    #pragma unroll
    for (int rd = 0; rd < 2; ++rd)
      GLOAD_LDS16(Wb + (size_t)(rd*8)*D_MODEL + ko, &Bs[(wid*16 + rd*8)*64]);
    __syncthreads();
    #pragma unroll
    for (int ks = 0; ks < 2; ++ks) {
      const int xc = ks ? x1 : x0;
      bf16x8 af[2], wf[4];
      #pragma unroll
      for (int i = 0; i < 2; ++i)
        af[i] = *reinterpret_cast<const bf16x8*>(&As[(wm + i*16 + lr)*64 + xc]);
      #pragma unroll
      for (int j = 0; j < 4; ++j)
        wf[j] = *reinterpret_cast<const bf16x8*>(&Bs[(j*16 + lr)*64 + xc]);
      #pragma unroll
      for (int i = 0; i < 2; ++i)
        #pragma unroll
        for (int j = 0; j < 4; ++j)
          acc[i][j] = __builtin_amdgcn_mfma_f32_16x16x32_bf16(wf[j], af[i], acc[i][j], 0, 0, 0);
    }
    __syncthreads();
  }

  #pragma unroll
  for (int i = 0; i < 2; ++i) {
    int m = m0 + wm + i*16 + lr;
    #pragma unroll
    for (int j = 0; j < 4; ++j) {
      int nb = n0 + j*16 + lc*4;
      float4 ov;
      ov.x = acc[i][j][0] + bop[nb  ];
      ov.y = acc[i][j][1] + bop[nb+1];
      ov.z = acc[i][j][2] + bop[nb+2];
      ov.w = acc[i][j][3] + bop[nb+3];
      *reinterpret_cast<float4*>(&outp[(size_t)m*D_MODEL + nb]) = ov;
    }
  }
}

// Flash attention v6: 32x32 MFMA, softmax row fully on lane-pair (l, l^32),
// P rebuilt in registers (cvt_pk + 4 shfl_xor(32)), ZERO LDS, K prefetched
// 1 tile ahead in registers. 1 wave/block, 2048 blocks, 32 q-rows per wave.
__global__ __launch_bounds__(64) void attn_fwd6(const ushort* __restrict__ Qh,
    const ushort* __restrict__ Kh, const ushort* __restrict__ Vt,
    ushort* __restrict__ ctx) {
  const int lane = threadIdx.x & 63;
  const int l31 = lane & 31, hh = lane >> 5;
  const int wg = blockIdx.x;
  const int u = (wg & 7) * 256 + (wg >> 3);   // XCD-chunked
  const int bh = u >> 6;
  const int sub = u & 63;
  const int q0 = (63 - sub) * 32;             // heavy-first within chunk
  const size_t base = (size_t)bh * T_SEQ * HD;
  const ushort* Qp = Qh + base;
  const ushort* Kp = Kh + base;
  const ushort* Vp = Vt + base;               // (hd, T) per bh

  const float S2 = SM_SCALE * LOG2E;
  const float A2 = ALIBI_M * LOG2E;
  const int qrow = q0 + l31;

  // Q fragments (B-operand, 32x32x16): col=q=l31, k(d) = c*16 + hh*8 + j
  bf16x8 qb[4];
  #pragma unroll
  for (int c = 0; c < 4; ++c)
    qb[c] = *reinterpret_cast<const bf16x8*>(&Qp[(size_t)qrow*HD + c*16 + hh*8]);

  float m_run = -1e30f;   // log2 domain
  float l_run = 0.f;
  f32x16 oT[2] = {};      // O^T: col q=l31, row d = dblk*32 + (reg&3)+8*(reg>>2)+4*hh

  const int t_hi = (q0 + 31) >> 6;
  const int t_lo = (q0 > WIN) ? ((q0 - WIN) >> 6) : 0;

  auto loadK = [&](bf16x8 (&KA)[2][4], int T) {
    const ushort* kp = Kp + (size_t)(T*64 + l31)*HD + hh*8;
    #pragma unroll
    for (int s = 0; s < 2; ++s)
      #pragma unroll
      for (int c = 0; c < 4; ++c)
        KA[s][c] = *reinterpret_cast<const bf16x8*>(kp + (size_t)s*32*HD + c*16);
  };

  auto tile = [&](const bf16x8 (&KA)[2][4], int T) {
    const int kb0 = T * 64;
    // V^T fragments (A-operand): row d = dblk*32+l31, k = kb0+s*32+ks*16+hh*8
    bf16x8 va[2][2][2];
    #pragma unroll
    for (int s = 0; s < 2; ++s)
      #pragma unroll
      for (int db = 0; db < 2; ++db)
        #pragma unroll
        for (int ks = 0; ks < 2; ++ks)
          va[s][db][ks] = *reinterpret_cast<const bf16x8*>(
              &Vp[(size_t)(db*32 + l31)*T_SEQ + kb0 + s*32 + ks*16 + hh*8]);

    #pragma unroll
    for (int s = 0; s < 2; ++s) {
      const int kbase = kb0 + s*32;
      if (kbase > q0 + 31) continue;          // wave-uniform skip
      // S^T = K @ Q^T : lane pair (l, l^32) holds row q=l31; own k = (reg&3)+8*(reg>>2)+4*hh
      f32x16 sa = {};
      __builtin_amdgcn_s_setprio(1);
      #pragma unroll
      for (int c = 0; c < 4; ++c)
        sa = __builtin_amdgcn_mfma_f32_32x32x16_bf16(KA[s][c], qb[c], sa, 0, 0, 0);
      __builtin_amdgcn_s_setprio(0);

      const int dq0 = kbase + 4*hh - qrow;
      const float ab = A2 * (float)dq0;
      const bool nm = (kbase + 31 > q0);
      float p[16];
      float pm = -1e30f;
      #pragma unroll
      for (int g = 0; g < 4; ++g)
        #pragma unroll
        for (int r = 0; r < 4; ++r) {
          const int off = r + 8*g;
          float val = fmaf(sa[g*4+r], S2, ab + A2*(float)off);
          if (nm && (dq0 + off > 0)) val = -1e30f;
          p[g*4+r] = val;
          pm = fmaxf(pm, val);
        }
      pm = fmaxf(pm, __shfl_xor(pm, 32));

      float ps = 0.f;
      if (__all(pm <= m_run)) {              // defer path (exact, diag-first)
        #pragma unroll
        for (int i = 0; i < 16; ++i) {
          p[i] = __builtin_amdgcn_exp2f(p[i] - m_run);
          ps += p[i];
        }
        ps += __shfl_xor(ps, 32);
        l_run += ps;
      } else {
        float mn = fmaxf(m_run, pm);
        float sc = __builtin_amdgcn_exp2f(m_run - mn);   // lane-local (col q)
        m_run = mn;
        #pragma unroll
        for (int i = 0; i < 16; ++i) {
          p[i] = __builtin_amdgcn_exp2f(p[i] - mn);
          ps += p[i];
        }
        ps += __shfl_xor(ps, 32);
        l_run = l_run * sc + ps;
        #pragma unroll
        for (int db = 0; db < 2; ++db)
          #pragma unroll
          for (int i = 0; i < 16; ++i) oT[db][i] *= sc;
      }

      // P -> B-fragments in registers.  own word w[j] covers k-pair:
      // h0: {0,1},{2,3},{8,9},{10,11},{16,17},{18,19},{24,25},{26,27}
      // h1: same +4.  Exchange 4 words with partner half (lane^32).
      unsigned w0 = cvtpk(p[0],  p[1]),  w1 = cvtpk(p[2],  p[3]);
      unsigned w2 = cvtpk(p[4],  p[5]),  w3 = cvtpk(p[6],  p[7]);
      unsigned w4 = cvtpk(p[8],  p[9]),  w5 = cvtpk(p[10], p[11]);
      unsigned w6 = cvtpk(p[12], p[13]), w7 = cvtpk(p[14], p[15]);
      unsigned x0 = __shfl_xor(hh ? w0 : w2, 32);
      unsigned x1 = __shfl_xor(hh ? w1 : w3, 32);
      unsigned x2 = __shfl_xor(hh ? w4 : w6, 32);
      unsigned x3 = __shfl_xor(hh ? w5 : w7, 32);
      union { unsigned u[4]; bf16x8 v; } pb0, pb1;
      pb0.u[0] = hh ? x0 : w0;  pb0.u[1] = hh ? x1 : w1;
      pb0.u[2] = hh ? w2 : x0;  pb0.u[3] = hh ? w3 : x1;
      pb1.u[0] = hh ? x2 : w4;  pb1.u[1] = hh ? x3 : w5;
      pb1.u[2] = hh ? w6 : x2;  pb1.u[3] = hh ? w7 : x3;

      __builtin_amdgcn_s_setprio(1);
      #pragma unroll
      for (int db = 0; db < 2; ++db) {
        oT[db] = __builtin_amdgcn_mfma_f32_32x32x16_bf16(va[s][db][0], pb0.v, oT[db], 0, 0, 0);
        oT[db] = __builtin_amdgcn_mfma_f32_32x32x16_bf16(va[s][db][1], pb1.v, oT[db], 0, 0, 0);
      }
      __builtin_amdgcn_s_setprio(0);
    }
  };

  bf16x8 ka0[2][4], ka1[2][4];
  int t = t_hi;
  loadK(ka0, t);
  for (;;) {
    bool has1 = (t - 1 >= t_lo);
    if (has1) loadK(ka1, t - 1);
    tile(ka0, t);
    if (!has1) break;
    bool has2 = (t - 2 >= t_lo);
    if (has2) loadK(ka0, t - 2);
    tile(ka1, t - 1);
    if (!has2) break;
    t -= 2;
  }

  // epilogue: lane-local normalize; packed uint2 stores (4 consecutive d per group)
  const int b = bh >> 4, hhead = bh & 15;
  const float inv = 1.f / l_run;
  #pragma unroll
  for (int db = 0; db < 2; ++db)
    #pragma unroll
    for (int g = 0; g < 4; ++g) {
      int d = db*32 + 8*g + 4*hh;
      uint2 ov;
      ov.x = cvtpk(oT[db][g*4+0]*inv, oT[db][g*4+1]*inv);
      ov.y = cvtpk(oT[db][g*4+2]*inv, oT[db][g*4+3]*inv);
      *reinterpret_cast<uint2*>(&ctx[((size_t)b*T_SEQ + qrow)*D_MODEL +
          hhead*HD + d]) = ov;
    }
}

extern "C" void kernel_launch(void* const* d_in, const int* in_sizes, int n_in,
                              void* d_out, int out_size, void* d_ws, size_t ws_size,
                              hipStream_t stream) {
  (void)in_sizes; (void)n_in; (void)out_size; (void)ws_size;
  const float* x  = (const float*)d_in[0];
  const float* Wq = (const float*)d_in[1];
  const float* bq = (const float*)d_in[2];
  const float* Wk = (const float*)d_in[3];
  const float* bk = (const float*)d_in[4];
  const float* Wv = (const float*)d_in[5];
  const float* bv = (const float*)d_in[6];
  const float* Wo = (const float*)d_in[7];
  const float* bo = (const float*)d_in[8];

  const size_t MB = 1ull << 20;
  char* ws = (char*)d_ws;
  ushort* xbf  = (ushort*)(ws);            // 8 MB
  ushort* wqkv = (ushort*)(ws + 8*MB);     // 6 MB  [3072][1024] bf16
  ushort* wob  = (ushort*)(ws + 14*MB);    // 2 MB
  ushort* Qh   = (ushort*)(ws + 16*MB);    // 8 MB (B,H,T,hd) Q; +8 MB K
  ushort* Vtb  = (ushort*)(ws + 32*MB);    // 8 MB (B,H,hd,T)
  ushort* ctx  = (ushort*)(ws + 40*MB);    // 8 MB (B,T,D)

  cvt_all<<<8192, 256, 0, stream>>>(x, Wq, Wk, Wv, Wo, xbf, wqkv, wob);

  gemm_qkv<<<dim3(24, 32), 256, 0, stream>>>(xbf, wqkv, bq, bk, bv, Qh, Vtb);

  attn_fwd6<<<dim3(2048), 64, 0, stream>>>(Qh, Qh + 4194304, Vtb, ctx);

  gemm_out<<<dim3(16, 32), 256, 0, stream>>>(ctx, wob, bo, (float*)d_out);
}